// Round 1
// 217.547 us; speedup vs baseline: 1.1122x; 1.1122x over previous
//
#include <hip/hip_runtime.h>
#include <math.h>

// NetVLAD: B=16, H=W=56 (HW=3136), D=512, K=32, fp32 in/out.
// Round 8: fuse k_s + k_ax into k_sax. Rationale: top-5 rocprof rows are all
// 392MiB harness poison fills @60us => every app kernel <60us; cost is the SUM
// of 4 launches moving ~280MB (x read TWICE, a round-trip, vpart round-trip)
// plus k_ax's LDS-bound VALU GEMM (336 ds_read_b128/thread ~= 24us floor).
// k_sax: phase-1 = R7's proven MFMA s-GEMM + softmax, but a goes to LDS
// (bf16 aT[k][pos]) instead of HBM; phase-2 = v[d,k] = sum_pos x[pos,d]*a[pos,k]
// as MFMA with A = xT (re-staged transposed, L2/L3-hot re-read) and B = aT.
// Slabs 28 -> 49 (one 64-pos chunk per block). a buffer deleted.
// k_norm1 (PS=49) / k_norm2 otherwise unchanged.

#define BATCH 16
#define HW    3136
#define DIM   512
#define KCL   32
#define NCHK  49                     // 64-pos chunks per batch (49*64 = 3136)

typedef __attribute__((ext_vector_type(8))) short short8;
typedef __attribute__((ext_vector_type(4))) float f32x4;

__device__ __forceinline__ void atomAddF(float* p, float v) {
    unsafeAtomicAdd(p, v);
}

__device__ __forceinline__ unsigned short f2bf(float f) {  // RNE fp32->bf16
    unsigned u = __float_as_uint(f);
    return (unsigned short)((u + 0x7FFFu + ((u >> 16) & 1u)) >> 16);
}

// ---------------- K1: s = x.Wc (MFMA) + softmax (in LDS) + v = xT.a --------
// grid 784 (= 16 b x 49 chunks), block 256 = 4 waves, 2 blocks/CU (57.5KB LDS).
// Phase-1 (verbatim R7 k_s): wave wv owns pos [wv*16,+16) x 32 k; K=512 staged
// in 4 LDS chunks of 128 d (bf16); frags A[m=lane&15][k=quad*8+j],
// B[k=quad*8+j][n=lane&15], D[row=quad*4+reg][col=lane&15] (m89/m120 layouts).
// Softmax result -> aT[k][pos] bf16 in LDS (never touches HBM).
// Phase-2: per 128-d chunk, re-stage x TRANSPOSED into the same xs buffer
// (xT[d][pos], row stride 80 shorts = 160B (16B-aligned b128 rows), pos XOR-
// swizzled by granule 8: pos^((d&7)<<3) => A-frag ds_read_b128 is 2-way (free)).
// MFMA: D[m=d][n=k] += A[d][pos].B[pos][k]; 8 mfma/wave/chunk; store slab.
#define XS_STR 136   // phase-1: shorts per pos row (128 d + 8 pad)
#define WT_STR 520   // shorts per k row of WcT (512 d + 8 pad)
#define AT_STR 72    // shorts per k row of aT  (64 pos + 8 pad)
#define XT_STR 80    // phase-2: shorts per d row of xT (64 pos + 16 pad; 160B)

__global__ __launch_bounds__(256, 2) void k_sax(const float* __restrict__ x,
                                                const float* __restrict__ Wc,
                                                float* __restrict__ vpart,
                                                float* __restrict__ a_sum) {
    __shared__ unsigned short xs[10240];          // 20480 B (union: [64][136] / [128][80])
    __shared__ unsigned short wt[32 * WT_STR];    // 33280 B
    __shared__ unsigned short aT[KCL * AT_STR];   //  4608 B
    __shared__ float asum_l[4][32];               //   512 B
    const int t    = threadIdx.x;
    const int lane = t & 63;
    const int wv   = t >> 6;
    const int l15  = lane & 15;
    const int quad = lane >> 4;
    const int n0   = blockIdx.x * 64;
    const int b    = n0 / HW;          // uniform per block (64 | 3136)
    const int ch   = blockIdx.x % NCHK;

    // ---- stage WcT[32 k][512 d] bf16, once (visible after first barrier#2)
#pragma unroll
    for (int i = 0; i < 16; ++i) {
        int f  = i * 256 + t;          // 0..4095 float4s of Wc
        int d  = f >> 3;               // 0..511
        int k4 = (f & 7) * 4;
        float4 v = *(const float4*)(Wc + (size_t)d * KCL + k4);
        wt[(k4 + 0) * WT_STR + d] = f2bf(v.x);
        wt[(k4 + 1) * WT_STR + d] = f2bf(v.y);
        wt[(k4 + 2) * WT_STR + d] = f2bf(v.z);
        wt[(k4 + 3) * WT_STR + d] = f2bf(v.w);
    }

    // ---- preload x chunk 0 (64 pos x 128 d fp32 = 8 float4/thread)
    float4 px[8];
#pragma unroll
    for (int i = 0; i < 8; ++i) {
        int f = i * 256 + t;           // pos = f>>5, c4 = (f&31)*4
        px[i] = *(const float4*)(x + ((size_t)(n0 + (f >> 5)) * DIM + (f & 31) * 4));
    }

    f32x4 acc0 = {0.f, 0.f, 0.f, 0.f};
    f32x4 acc1 = {0.f, 0.f, 0.f, 0.f};

    for (int c = 0; c < 4; ++c) {
        __syncthreads();
#pragma unroll
        for (int i = 0; i < 8; ++i) {
            int f = i * 256 + t;
            ushort4 w;
            w.x = f2bf(px[i].x); w.y = f2bf(px[i].y);
            w.z = f2bf(px[i].z); w.w = f2bf(px[i].w);
            *(ushort4*)&xs[(f >> 5) * XS_STR + (f & 31) * 4] = w;
        }
        __syncthreads();
        if (c < 3) {                   // prefetch next d-chunk
            const int dc = (c + 1) * 128;
#pragma unroll
            for (int i = 0; i < 8; ++i) {
                int f = i * 256 + t;
                px[i] = *(const float4*)(x + ((size_t)(n0 + (f >> 5)) * DIM + dc + (f & 31) * 4));
            }
        }
        const int dc = c * 128;
#pragma unroll
        for (int ds = 0; ds < 4; ++ds) {
            const int dloc = ds * 32 + quad * 8;
            short8 af = *(const short8*)&xs[(wv * 16 + l15) * XS_STR + dloc];
            short8 b0 = *(const short8*)&wt[l15 * WT_STR + dc + dloc];
            short8 b1 = *(const short8*)&wt[(16 + l15) * WT_STR + dc + dloc];
            acc0 = __builtin_amdgcn_mfma_f32_16x16x32_bf16(af, b0, acc0, 0, 0, 0);
            acc1 = __builtin_amdgcn_mfma_f32_16x16x32_bf16(af, b1, acc1, 0, 0, 0);
        }
    }

    // ---- softmax over 32 k per position (row = quad*4+reg, col k = l15/+16)
    // a -> aT[k][pos] bf16 in LDS (phase-2 B operand); a_sum via block atomic.
    float at0 = 0.f, at1 = 0.f;
#pragma unroll
    for (int r = 0; r < 4; ++r) {
        float m = fmaxf(acc0[r], acc1[r]);
        m = fmaxf(m, __shfl_xor(m, 1));
        m = fmaxf(m, __shfl_xor(m, 2));
        m = fmaxf(m, __shfl_xor(m, 4));
        m = fmaxf(m, __shfl_xor(m, 8));
        float e0 = __expf(acc0[r] - m);
        float e1 = __expf(acc1[r] - m);
        float s = e0 + e1;
        s += __shfl_xor(s, 1);
        s += __shfl_xor(s, 2);
        s += __shfl_xor(s, 4);
        s += __shfl_xor(s, 8);
        float inv = 1.f / s;
        float a0 = e0 * inv, a1 = e1 * inv;
        const int pos = wv * 16 + quad * 4 + r;        // local 0..63
        aT[l15 * AT_STR + pos]        = f2bf(a0);
        aT[(16 + l15) * AT_STR + pos] = f2bf(a1);
        at0 += a0; at1 += a1;
    }
    at0 += __shfl_xor(at0, 16); at0 += __shfl_xor(at0, 32);
    at1 += __shfl_xor(at1, 16); at1 += __shfl_xor(at1, 32);
    if (quad == 0) {
        asum_l[wv][l15]      = at0;
        asum_l[wv][16 + l15] = at1;
    }

    // ---- phase-2 prefetch chunk 0 (independent of LDS; overlaps the barrier)
    const int dl  = t & 127;           // local d row this thread stages
    const int pg0 = t >> 7;            // 0/1: which half of the 4-pos groups
    const float* xb = x + (size_t)n0 * DIM + dl;
    float pf[32];
#pragma unroll
    for (int i = 0; i < 8; ++i) {
        const int p = (pg0 + 2 * i) * 4;
#pragma unroll
        for (int j = 0; j < 4; ++j)
            pf[i * 4 + j] = xb[(size_t)(p + j) * DIM];
    }

    __syncthreads();
    if (t < 32)
        atomAddF(&a_sum[b * KCL + t],
                 asum_l[0][t] + asum_l[1][t] + asum_l[2][t] + asum_l[3][t]);

    // ---- phase-2: v[d,k] = sum_pos x[pos,d]*a[pos,k], 4 chunks of 128 d
    float* vp = vpart + (size_t)ch * (BATCH * DIM * KCL) + (size_t)b * DIM * KCL;
    for (int dc = 0; dc < DIM; dc += 128) {
        __syncthreads();               // prior chunk's MFMA reads done
#pragma unroll
        for (int i = 0; i < 8; ++i) {  // stage xT[d][pos] (XOR-swizzled pos)
            const int p = (pg0 + 2 * i) * 4;
            ushort4 w;
            w.x = f2bf(pf[i * 4 + 0]);
            w.y = f2bf(pf[i * 4 + 1]);
            w.z = f2bf(pf[i * 4 + 2]);
            w.w = f2bf(pf[i * 4 + 3]);
            *(ushort4*)&xs[dl * XT_STR + (p ^ ((dl & 7) << 3))] = w;
        }
        __syncthreads();
        if (dc < 384) {                // prefetch next chunk (L2/L3-hot)
            const int dn = dc + 128;
#pragma unroll
            for (int i = 0; i < 8; ++i) {
                const int p = (pg0 + 2 * i) * 4;
#pragma unroll
                for (int j = 0; j < 4; ++j)
                    pf[i * 4 + j] = xb[(size_t)(p + j) * DIM + dn];
            }
        }
        f32x4 z = {0.f, 0.f, 0.f, 0.f};
        f32x4 pacc[2][2];
        pacc[0][0] = z; pacc[0][1] = z; pacc[1][0] = z; pacc[1][1] = z;
#pragma unroll
        for (int s = 0; s < 2; ++s) {  // kd = pos, 2 steps of 32
            const int pb = s * 32 + quad * 8;
            short8 bf0 = *(const short8*)&aT[l15 * AT_STR + pb];
            short8 bf1 = *(const short8*)&aT[(16 + l15) * AT_STR + pb];
#pragma unroll
            for (int m2 = 0; m2 < 2; ++m2) {
                const int dloc = (wv * 2 + m2) * 16 + l15;
                short8 af = *(const short8*)&xs[dloc * XT_STR + (pb ^ ((dloc & 7) << 3))];
                pacc[m2][0] = __builtin_amdgcn_mfma_f32_16x16x32_bf16(af, bf0, pacc[m2][0], 0, 0, 0);
                pacc[m2][1] = __builtin_amdgcn_mfma_f32_16x16x32_bf16(af, bf1, pacc[m2][1], 0, 0, 0);
            }
        }
#pragma unroll
        for (int m2 = 0; m2 < 2; ++m2) {   // D[row=quad*4+r -> d][col=l15 -> k]
            const int dr = dc + (wv * 2 + m2) * 16 + quad * 4;
#pragma unroll
            for (int r = 0; r < 4; ++r) {
                vp[(size_t)(dr + r) * KCL + l15]      = pacc[m2][0][r];
                vp[(size_t)(dr + r) * KCL + 16 + l15] = pacc[m2][1][r];
            }
        }
    }
}

// ---------------- K3: reduce chunk slabs + C*a_sum + intra-normalize -------
// grid 2048, block 128: 4 rows x 32 k; thread = one (row,k) cell.
__global__ __launch_bounds__(128) void k_norm1(const float* __restrict__ vpart,
                                               const float* __restrict__ a_sum,
                                               const float* __restrict__ Cc,
                                               float* __restrict__ out,
                                               float* __restrict__ ssq, int PS) {
    const int t = threadIdx.x;
    const int row = blockIdx.x * 4 + (t >> 5);
    const int k = t & 31;
    const int b = row >> 9;
    const int d = row & 511;

    float sum = 0.f;
    for (int ps = 0; ps < PS; ++ps)
        sum += vpart[(size_t)ps * BATCH * DIM * KCL + (size_t)row * KCL + k];
    float v = sum + Cc[d * KCL + k] * a_sum[b * KCL + k];

    float ss = v * v;
    ss += __shfl_xor(ss, 1, 32);  ss += __shfl_xor(ss, 2, 32);
    ss += __shfl_xor(ss, 4, 32);  ss += __shfl_xor(ss, 8, 32);
    ss += __shfl_xor(ss, 16, 32);
    float inv = 1.f / fmaxf(sqrtf(ss), 1e-12f);
    float r = v * inv;
    out[(size_t)row * KCL + k] = r;

    float bs = r * r;
    for (int off = 32; off > 0; off >>= 1) bs += __shfl_down(bs, off, 64);
    __shared__ float red[2];
    if ((t & 63) == 0) red[t >> 6] = bs;
    __syncthreads();
    if (t == 0) atomAddF(&ssq[b], red[0] + red[1]);
}

// ---------------- K4: final global L2 normalize ----------------
__global__ __launch_bounds__(256) void k_norm2(float* __restrict__ out,
                                               const float* __restrict__ ssq) {
    const int i4 = blockIdx.x * 256 + threadIdx.x;
    const int b = i4 >> 12;
    float inv = 1.f / fmaxf(sqrtf(ssq[b]), 1e-12f);
    float4 v = *(float4*)(out + (size_t)i4 * 4);
    v.x *= inv; v.y *= inv; v.z *= inv; v.w *= inv;
    *(float4*)(out + (size_t)i4 * 4) = v;
}

extern "C" void kernel_launch(void* const* d_in, const int* in_sizes, int n_in,
                              void* d_out, int out_size, void* d_ws, size_t ws_size,
                              hipStream_t stream) {
    const float* x  = (const float*)d_in[0];
    const float* Wc = (const float*)d_in[1];
    const float* Cc = (const float*)d_in[2];
    float* out = (float*)d_out;

    // ws: vpart 49 slabs (51.4 MB) | a_sum (2 KB) | ssq (64 B)
    const size_t SLAB = (size_t)BATCH * DIM * KCL * 4;   // 1,048,576
    char* ws = (char*)d_ws;
    float* vpart = (float*)ws;
    float* a_sum = (float*)(ws + (size_t)NCHK * SLAB);
    float* ssq   = (float*)(ws + (size_t)NCHK * SLAB + 2048);

    hipMemsetAsync(a_sum, 0, 2048 + 64, stream);

    k_sax  <<<784, 256, 0, stream>>>(x, Wc, vpart, a_sum);
    k_norm1<<<2048, 128, 0, stream>>>(vpart, a_sum, Cc, out, ssq, NCHK);
    k_norm2<<<256, 256, 0, stream>>>(out, ssq);
}

// Round 2
// 216.378 us; speedup vs baseline: 1.1182x; 1.0054x over previous
//
#include <hip/hip_runtime.h>
#include <math.h>

// NetVLAD: B=16, H=W=56 (HW=3136), D=512, K=32, fp32 in/out.
// Round 9: occupancy fix. R8 counters: k_sax 64.7us @ 28% HBM, MfmaUtil 1.8%,
// VALUBusy 10.5%, Occupancy 15.5% => latency-bound, LDS-capped at 2 blocks/CU
// (58880B). The hog was wt: full 512-d Wc transpose (33KB) staged per block,
// though (a) MFMA touches one 128-d chunk at a time and (b) Wc is 64KB and
// L2-resident for all 784 blocks. Now wt is staged PER CHUNK (8.7KB), phase-2
// xT stride compacted 80->72 shorts (swizzle granule (dl>>3)&7; frag reads
// stay 2-way/free), total LDS 32256B => 5 blocks/CU (20 waves/CU). Wc chunk
// loads issue before the barrier so latency folds into the existing drain.
// Also: vpart slabs padded +1KB to break the 1MB power-of-2 stride in
// k_norm1's 49-way reduction (L2 channel aliasing guard).

#define BATCH 16
#define HW    3136
#define DIM   512
#define KCL   32
#define NCHK  49                     // 64-pos chunks per batch (49*64 = 3136)
#define SLABF (BATCH * DIM * KCL + 256)   // padded slab stride in floats

typedef __attribute__((ext_vector_type(8))) short short8;
typedef __attribute__((ext_vector_type(4))) float f32x4;

__device__ __forceinline__ void atomAddF(float* p, float v) {
    unsafeAtomicAdd(p, v);
}

__device__ __forceinline__ unsigned short f2bf(float f) {  // RNE fp32->bf16
    unsigned u = __float_as_uint(f);
    return (unsigned short)((u + 0x7FFFu + ((u >> 16) & 1u)) >> 16);
}

// ---------------- K1: s = x.Wc (MFMA) + softmax (in LDS) + v = xT.a --------
// grid 784 (= 16 b x 49 chunks), block 256 = 4 waves, 5 blocks/CU (31.5KB LDS).
// Phase-1: wave wv owns pos [wv*16,+16) x 32 k; K=512 in 4 chunks of 128 d
// (bf16); Wc chunk staged per c. Frags A[m=lane&15][k=quad*8+j],
// B[k=quad*8+j][n=lane&15], D[row=quad*4+reg][col=lane&15] (m89/m120 layouts).
// Softmax -> aT[k][pos] bf16 in LDS. Phase-2: per 128-d chunk, re-stage x
// TRANSPOSED (L2/L3-hot re-read) as xT[d][pos], row stride 72 shorts (144B,
// 16B-aligned rows), pos XOR-swizzled granule 8 by (dl>>3)&7 => A-frag
// ds_read_b128 ~2-way (free). MFMA D[m=d][n=k] += A[d][pos].B[pos][k].
#define XS_STR  136   // phase-1: shorts per pos row (128 d + 8 pad)
#define WTC_STR 136   // per-chunk WcT: shorts per k row (128 d + 8 pad)
#define AT_STR  72    // shorts per k row of aT  (64 pos + 8 pad)
#define XT_STR  72    // phase-2: shorts per d row of xT (64 pos + 8 pad)

__global__ __launch_bounds__(256, 5) void k_sax(const float* __restrict__ x,
                                                const float* __restrict__ Wc,
                                                float* __restrict__ vpart,
                                                float* __restrict__ a_sum) {
    __shared__ unsigned short xs[9216];           // 18432 B ([64][136] / [128][72])
    __shared__ unsigned short wt[32 * WTC_STR];   //  8704 B
    __shared__ unsigned short aT[KCL * AT_STR];   //  4608 B
    __shared__ float asum_l[4][32];               //   512 B
    const int t    = threadIdx.x;
    const int lane = t & 63;
    const int wv   = t >> 6;
    const int l15  = lane & 15;
    const int quad = lane >> 4;
    const int n0   = blockIdx.x * 64;
    const int b    = n0 / HW;          // uniform per block (64 | 3136)
    const int ch   = blockIdx.x % NCHK;

    // ---- preload x chunk 0 (64 pos x 128 d fp32 = 8 float4/thread)
    float4 px[8];
#pragma unroll
    for (int i = 0; i < 8; ++i) {
        int f = i * 256 + t;           // pos = f>>5, c4 = (f&31)*4
        px[i] = *(const float4*)(x + ((size_t)(n0 + (f >> 5)) * DIM + (f & 31) * 4));
    }

    f32x4 acc0 = {0.f, 0.f, 0.f, 0.f};
    f32x4 acc1 = {0.f, 0.f, 0.f, 0.f};

    for (int c = 0; c < 4; ++c) {
        const int dc = c * 128;
        // Wc chunk loads: issued before the barrier; latency folds into the
        // vmcnt drain the barrier performs anyway. L2-hot (Wc = 64KB shared).
        float4 wc4[4];
#pragma unroll
        for (int i = 0; i < 4; ++i) {
            int f = i * 256 + t;       // 0..1023: d = f>>3 (0..127), k4 = (f&7)*4
            wc4[i] = *(const float4*)(Wc + (size_t)(dc + (f >> 3)) * KCL + (f & 7) * 4);
        }
        __syncthreads();
#pragma unroll
        for (int i = 0; i < 8; ++i) {
            int f = i * 256 + t;
            ushort4 w;
            w.x = f2bf(px[i].x); w.y = f2bf(px[i].y);
            w.z = f2bf(px[i].z); w.w = f2bf(px[i].w);
            *(ushort4*)&xs[(f >> 5) * XS_STR + (f & 31) * 4] = w;
        }
#pragma unroll
        for (int i = 0; i < 4; ++i) {
            int f  = i * 256 + t;
            int d  = f >> 3;
            int k4 = (f & 7) * 4;
            wt[(k4 + 0) * WTC_STR + d] = f2bf(wc4[i].x);
            wt[(k4 + 1) * WTC_STR + d] = f2bf(wc4[i].y);
            wt[(k4 + 2) * WTC_STR + d] = f2bf(wc4[i].z);
            wt[(k4 + 3) * WTC_STR + d] = f2bf(wc4[i].w);
        }
        __syncthreads();
        if (c < 3) {                   // prefetch next x d-chunk
            const int dn = dc + 128;
#pragma unroll
            for (int i = 0; i < 8; ++i) {
                int f = i * 256 + t;
                px[i] = *(const float4*)(x + ((size_t)(n0 + (f >> 5)) * DIM + dn + (f & 31) * 4));
            }
        }
#pragma unroll
        for (int ds = 0; ds < 4; ++ds) {
            const int dloc = ds * 32 + quad * 8;
            short8 af = *(const short8*)&xs[(wv * 16 + l15) * XS_STR + dloc];
            short8 b0 = *(const short8*)&wt[l15 * WTC_STR + dloc];
            short8 b1 = *(const short8*)&wt[(16 + l15) * WTC_STR + dloc];
            acc0 = __builtin_amdgcn_mfma_f32_16x16x32_bf16(af, b0, acc0, 0, 0, 0);
            acc1 = __builtin_amdgcn_mfma_f32_16x16x32_bf16(af, b1, acc1, 0, 0, 0);
        }
    }

    // ---- softmax over 32 k per position (row = quad*4+reg, col k = l15/+16)
    // a -> aT[k][pos] bf16 in LDS (phase-2 B operand); a_sum via block atomic.
    float at0 = 0.f, at1 = 0.f;
#pragma unroll
    for (int r = 0; r < 4; ++r) {
        float m = fmaxf(acc0[r], acc1[r]);
        m = fmaxf(m, __shfl_xor(m, 1));
        m = fmaxf(m, __shfl_xor(m, 2));
        m = fmaxf(m, __shfl_xor(m, 4));
        m = fmaxf(m, __shfl_xor(m, 8));
        float e0 = __expf(acc0[r] - m);
        float e1 = __expf(acc1[r] - m);
        float s = e0 + e1;
        s += __shfl_xor(s, 1);
        s += __shfl_xor(s, 2);
        s += __shfl_xor(s, 4);
        s += __shfl_xor(s, 8);
        float inv = 1.f / s;
        float a0 = e0 * inv, a1 = e1 * inv;
        const int pos = wv * 16 + quad * 4 + r;        // local 0..63
        aT[l15 * AT_STR + pos]        = f2bf(a0);
        aT[(16 + l15) * AT_STR + pos] = f2bf(a1);
        at0 += a0; at1 += a1;
    }
    at0 += __shfl_xor(at0, 16); at0 += __shfl_xor(at0, 32);
    at1 += __shfl_xor(at1, 16); at1 += __shfl_xor(at1, 32);
    if (quad == 0) {
        asum_l[wv][l15]      = at0;
        asum_l[wv][16 + l15] = at1;
    }

    // ---- phase-2 prefetch chunk 0 (independent of LDS; overlaps the barrier)
    const int dl  = t & 127;           // local d row this thread stages
    const int pg0 = t >> 7;            // 0/1: which half of the 4-pos groups
    const float* xb = x + (size_t)n0 * DIM + dl;
    float pf[32];
#pragma unroll
    for (int i = 0; i < 8; ++i) {
        const int p = (pg0 + 2 * i) * 4;
#pragma unroll
        for (int j = 0; j < 4; ++j)
            pf[i * 4 + j] = xb[(size_t)(p + j) * DIM];
    }

    __syncthreads();
    if (t < 32)
        atomAddF(&a_sum[b * KCL + t],
                 asum_l[0][t] + asum_l[1][t] + asum_l[2][t] + asum_l[3][t]);

    // ---- phase-2: v[d,k] = sum_pos x[pos,d]*a[pos,k], 4 chunks of 128 d
    float* vp = vpart + (size_t)ch * SLABF + (size_t)b * DIM * KCL;
    for (int dc = 0; dc < DIM; dc += 128) {
        __syncthreads();               // prior chunk's MFMA reads done
#pragma unroll
        for (int i = 0; i < 8; ++i) {  // stage xT[d][pos] (XOR-swizzled pos)
            const int p = (pg0 + 2 * i) * 4;
            ushort4 w;
            w.x = f2bf(pf[i * 4 + 0]);
            w.y = f2bf(pf[i * 4 + 1]);
            w.z = f2bf(pf[i * 4 + 2]);
            w.w = f2bf(pf[i * 4 + 3]);
            *(ushort4*)&xs[dl * XT_STR + (p ^ (((dl >> 3) & 7) << 3))] = w;
        }
        __syncthreads();
        if (dc < 384) {                // prefetch next chunk (L2/L3-hot)
            const int dn = dc + 128;
#pragma unroll
            for (int i = 0; i < 8; ++i) {
                const int p = (pg0 + 2 * i) * 4;
#pragma unroll
                for (int j = 0; j < 4; ++j)
                    pf[i * 4 + j] = xb[(size_t)(p + j) * DIM + dn];
            }
        }
        f32x4 z = {0.f, 0.f, 0.f, 0.f};
        f32x4 pacc[2][2];
        pacc[0][0] = z; pacc[0][1] = z; pacc[1][0] = z; pacc[1][1] = z;
#pragma unroll
        for (int s = 0; s < 2; ++s) {  // kd = pos, 2 steps of 32
            const int pb = s * 32 + quad * 8;
            short8 bf0 = *(const short8*)&aT[l15 * AT_STR + pb];
            short8 bf1 = *(const short8*)&aT[(16 + l15) * AT_STR + pb];
#pragma unroll
            for (int m2 = 0; m2 < 2; ++m2) {
                const int dloc = (wv * 2 + m2) * 16 + l15;
                short8 af = *(const short8*)&xs[dloc * XT_STR + (pb ^ (((dloc >> 3) & 7) << 3))];
                pacc[m2][0] = __builtin_amdgcn_mfma_f32_16x16x32_bf16(af, bf0, pacc[m2][0], 0, 0, 0);
                pacc[m2][1] = __builtin_amdgcn_mfma_f32_16x16x32_bf16(af, bf1, pacc[m2][1], 0, 0, 0);
            }
        }
#pragma unroll
        for (int m2 = 0; m2 < 2; ++m2) {   // D[row=quad*4+r -> d][col=l15 -> k]
            const int dr = dc + (wv * 2 + m2) * 16 + quad * 4;
#pragma unroll
            for (int r = 0; r < 4; ++r) {
                vp[(size_t)(dr + r) * KCL + l15]      = pacc[m2][0][r];
                vp[(size_t)(dr + r) * KCL + 16 + l15] = pacc[m2][1][r];
            }
        }
    }
}

// ---------------- K3: reduce chunk slabs + C*a_sum + intra-normalize -------
// grid 2048, block 128: 4 rows x 32 k; thread = one (row,k) cell.
__global__ __launch_bounds__(128) void k_norm1(const float* __restrict__ vpart,
                                               const float* __restrict__ a_sum,
                                               const float* __restrict__ Cc,
                                               float* __restrict__ out,
                                               float* __restrict__ ssq, int PS) {
    const int t = threadIdx.x;
    const int row = blockIdx.x * 4 + (t >> 5);
    const int k = t & 31;
    const int b = row >> 9;
    const int d = row & 511;

    float sum = 0.f;
    for (int ps = 0; ps < PS; ++ps)
        sum += vpart[(size_t)ps * SLABF + (size_t)row * KCL + k];
    float v = sum + Cc[d * KCL + k] * a_sum[b * KCL + k];

    float ss = v * v;
    ss += __shfl_xor(ss, 1, 32);  ss += __shfl_xor(ss, 2, 32);
    ss += __shfl_xor(ss, 4, 32);  ss += __shfl_xor(ss, 8, 32);
    ss += __shfl_xor(ss, 16, 32);
    float inv = 1.f / fmaxf(sqrtf(ss), 1e-12f);
    float r = v * inv;
    out[(size_t)row * KCL + k] = r;

    float bs = r * r;
    for (int off = 32; off > 0; off >>= 1) bs += __shfl_down(bs, off, 64);
    __shared__ float red[2];
    if ((t & 63) == 0) red[t >> 6] = bs;
    __syncthreads();
    if (t == 0) atomAddF(&ssq[b], red[0] + red[1]);
}

// ---------------- K4: final global L2 normalize ----------------
__global__ __launch_bounds__(256) void k_norm2(float* __restrict__ out,
                                               const float* __restrict__ ssq) {
    const int i4 = blockIdx.x * 256 + threadIdx.x;
    const int b = i4 >> 12;
    float inv = 1.f / fmaxf(sqrtf(ssq[b]), 1e-12f);
    float4 v = *(float4*)(out + (size_t)i4 * 4);
    v.x *= inv; v.y *= inv; v.z *= inv; v.w *= inv;
    *(float4*)(out + (size_t)i4 * 4) = v;
}

extern "C" void kernel_launch(void* const* d_in, const int* in_sizes, int n_in,
                              void* d_out, int out_size, void* d_ws, size_t ws_size,
                              hipStream_t stream) {
    const float* x  = (const float*)d_in[0];
    const float* Wc = (const float*)d_in[1];
    const float* Cc = (const float*)d_in[2];
    float* out = (float*)d_out;

    // ws: vpart 49 padded slabs (51.5 MB) | a_sum (2 KB) | ssq (64 B)
    char* ws = (char*)d_ws;
    float* vpart = (float*)ws;
    float* a_sum = (float*)(ws + (size_t)NCHK * SLABF * 4);
    float* ssq   = (float*)(ws + (size_t)NCHK * SLABF * 4 + 2048);

    hipMemsetAsync(a_sum, 0, 2048 + 64, stream);

    k_sax  <<<784, 256, 0, stream>>>(x, Wc, vpart, a_sum);
    k_norm1<<<2048, 128, 0, stream>>>(vpart, a_sum, Cc, out, ssq, NCHK);
    k_norm2<<<256, 256, 0, stream>>>(out, ssq);
}

// Round 3
// 195.125 us; speedup vs baseline: 1.2400x; 1.1089x over previous
//
#include <hip/hip_runtime.h>
#include <math.h>

// NetVLAD: B=16, H=W=56 (HW=3136), D=512, K=32, fp32 in/out.
// Round 10: break the convoy. R9 counters: dur flat at 65us despite occupancy
// 15.5->26.9%; VGPR collapsed 88->48 => launch_bounds(256,5)'s ~96-VGPR cap
// made the compiler SINK the px/pf/wc prefetches (pipeline deleted); and
// hbm_bytes/dur = 2.38 TB/s exactly => k_sax moves minimum bytes at a 38%
// HBM duty cycle (all 784 blocks flood-then-drain in lockstep). Fixes:
//  - launch_bounds(256,3) (~168 VGPR budget) + 2-chunk-deep prefetch in both
//    phases, fully unrolled (static indices; rule: runtime-indexed arrays
//    spill to scratch). Load->use distance = one full chunk phase.
//  - k_norm1: compile-time 49-slab loop, unroll x4, 4 accumulators (the
//    runtime-bound loop serialized ~49 L3 hits/thread); block 256, grid 1024.

#define BATCH 16
#define HW    3136
#define DIM   512
#define KCL   32
#define NCHK  49                     // 64-pos chunks per batch (49*64 = 3136)
#define SLABF (BATCH * DIM * KCL + 256)   // padded slab stride in floats

typedef __attribute__((ext_vector_type(8))) short short8;
typedef __attribute__((ext_vector_type(4))) float f32x4;

__device__ __forceinline__ void atomAddF(float* p, float v) {
    unsafeAtomicAdd(p, v);
}

__device__ __forceinline__ unsigned short f2bf(float f) {  // RNE fp32->bf16
    unsigned u = __float_as_uint(f);
    return (unsigned short)((u + 0x7FFFu + ((u >> 16) & 1u)) >> 16);
}

// ---------------- K1: s = x.Wc (MFMA) + softmax (in LDS) + v = xT.a --------
// grid 784 (= 16 b x 49 chunks), block 256 = 4 waves, 3 blocks/CU (VGPR-capped;
// grid supplies 3.06/CU anyway). LDS 31.5KB. Phase-1: wave wv owns pos
// [wv*16,+16) x 32 k; K=512 in 4 chunks of 128 d (bf16), Wc chunk staged per c.
// Frags A[m=lane&15][k=quad*8+j], B[k=quad*8+j][n=lane&15],
// D[row=quad*4+reg][col=lane&15] (m89/m120 layouts). Softmax -> aT[k][pos]
// bf16 in LDS. Phase-2: per 128-d chunk, re-stage x TRANSPOSED (L2/L3-hot
// re-read) as xT[d][pos], stride 72 shorts, pos XOR-swizzled granule 8 by
// (dl>>3)&7 => frag ds_read_b128 ~2-way (free). Both phases: 2-deep prefetch.
#define XS_STR  136   // phase-1: shorts per pos row (128 d + 8 pad)
#define WTC_STR 136   // per-chunk WcT: shorts per k row (128 d + 8 pad)
#define AT_STR  72    // shorts per k row of aT  (64 pos + 8 pad)
#define XT_STR  72    // phase-2: shorts per d row of xT (64 pos + 8 pad)

#define LOAD_PX(PX, DC)                                                        \
    _Pragma("unroll")                                                          \
    for (int i = 0; i < 8; ++i) {                                              \
        int f = i * 256 + t;                                                   \
        PX[i] = *(const float4*)(x + ((size_t)(n0 + (f >> 5)) * DIM + (DC) + (f & 31) * 4)); \
    }

#define LOAD_WC(WC, DC)                                                        \
    _Pragma("unroll")                                                          \
    for (int i = 0; i < 4; ++i) {                                              \
        int f = i * 256 + t;                                                   \
        WC[i] = *(const float4*)(Wc + (size_t)((DC) + (f >> 3)) * KCL + (f & 7) * 4); \
    }

#define P1_STAGE(PX, WC)                                                       \
    __syncthreads();                                                           \
    _Pragma("unroll")                                                          \
    for (int i = 0; i < 8; ++i) {                                              \
        int f = i * 256 + t;                                                   \
        ushort4 w;                                                             \
        w.x = f2bf(PX[i].x); w.y = f2bf(PX[i].y);                              \
        w.z = f2bf(PX[i].z); w.w = f2bf(PX[i].w);                              \
        *(ushort4*)&xs[(f >> 5) * XS_STR + (f & 31) * 4] = w;                  \
    }                                                                          \
    _Pragma("unroll")                                                          \
    for (int i = 0; i < 4; ++i) {                                              \
        int f  = i * 256 + t;                                                  \
        int d  = f >> 3;                                                       \
        int k4 = (f & 7) * 4;                                                  \
        wt[(k4 + 0) * WTC_STR + d] = f2bf(WC[i].x);                            \
        wt[(k4 + 1) * WTC_STR + d] = f2bf(WC[i].y);                            \
        wt[(k4 + 2) * WTC_STR + d] = f2bf(WC[i].z);                            \
        wt[(k4 + 3) * WTC_STR + d] = f2bf(WC[i].w);                            \
    }                                                                          \
    __syncthreads();

#define P1_MFMA()                                                              \
    _Pragma("unroll")                                                          \
    for (int ds_ = 0; ds_ < 4; ++ds_) {                                        \
        const int dloc = ds_ * 32 + quad * 8;                                  \
        short8 af = *(const short8*)&xs[(wv * 16 + l15) * XS_STR + dloc];      \
        short8 b0 = *(const short8*)&wt[l15 * WTC_STR + dloc];                 \
        short8 b1 = *(const short8*)&wt[(16 + l15) * WTC_STR + dloc];          \
        acc0 = __builtin_amdgcn_mfma_f32_16x16x32_bf16(af, b0, acc0, 0, 0, 0); \
        acc1 = __builtin_amdgcn_mfma_f32_16x16x32_bf16(af, b1, acc1, 0, 0, 0); \
    }

#define LOAD_PF(PF, DC)                                                        \
    _Pragma("unroll")                                                          \
    for (int i = 0; i < 8; ++i) {                                              \
        const int p = (pg0 + 2 * i) * 4;                                       \
        _Pragma("unroll")                                                      \
        for (int j = 0; j < 4; ++j)                                            \
            PF[i * 4 + j] = xb[(size_t)(p + j) * DIM + (DC)];                  \
    }

#define P2_STAGE(PF)                                                           \
    __syncthreads();                                                           \
    _Pragma("unroll")                                                          \
    for (int i = 0; i < 8; ++i) {                                              \
        const int p = (pg0 + 2 * i) * 4;                                       \
        ushort4 w;                                                             \
        w.x = f2bf(PF[i * 4 + 0]); w.y = f2bf(PF[i * 4 + 1]);                  \
        w.z = f2bf(PF[i * 4 + 2]); w.w = f2bf(PF[i * 4 + 3]);                  \
        *(ushort4*)&xs[dl * XT_STR + (p ^ (((dl >> 3) & 7) << 3))] = w;        \
    }                                                                          \
    __syncthreads();

#define P2_MFMA_STORE(DC)                                                      \
    {                                                                          \
        f32x4 z = {0.f, 0.f, 0.f, 0.f};                                        \
        f32x4 pacc[2][2];                                                      \
        pacc[0][0] = z; pacc[0][1] = z; pacc[1][0] = z; pacc[1][1] = z;        \
        _Pragma("unroll")                                                      \
        for (int s_ = 0; s_ < 2; ++s_) {                                       \
            const int pb = s_ * 32 + quad * 8;                                 \
            short8 bf0 = *(const short8*)&aT[l15 * AT_STR + pb];               \
            short8 bf1 = *(const short8*)&aT[(16 + l15) * AT_STR + pb];        \
            _Pragma("unroll")                                                  \
            for (int m2 = 0; m2 < 2; ++m2) {                                   \
                const int dloc = (wv * 2 + m2) * 16 + l15;                     \
                short8 af = *(const short8*)&xs[dloc * XT_STR + (pb ^ (((dloc >> 3) & 7) << 3))]; \
                pacc[m2][0] = __builtin_amdgcn_mfma_f32_16x16x32_bf16(af, bf0, pacc[m2][0], 0, 0, 0); \
                pacc[m2][1] = __builtin_amdgcn_mfma_f32_16x16x32_bf16(af, bf1, pacc[m2][1], 0, 0, 0); \
            }                                                                  \
        }                                                                      \
        _Pragma("unroll")                                                      \
        for (int m2 = 0; m2 < 2; ++m2) {                                       \
            const int dr = (DC) + (wv * 2 + m2) * 16 + quad * 4;               \
            _Pragma("unroll")                                                  \
            for (int r = 0; r < 4; ++r) {                                      \
                vp[(size_t)(dr + r) * KCL + l15]      = pacc[m2][0][r];        \
                vp[(size_t)(dr + r) * KCL + 16 + l15] = pacc[m2][1][r];        \
            }                                                                  \
        }                                                                      \
    }

__global__ __launch_bounds__(256, 3) void k_sax(const float* __restrict__ x,
                                                const float* __restrict__ Wc,
                                                float* __restrict__ vpart,
                                                float* __restrict__ a_sum) {
    __shared__ unsigned short xs[9216];           // 18432 B ([64][136] / [128][72])
    __shared__ unsigned short wt[32 * WTC_STR];   //  8704 B
    __shared__ unsigned short aT[KCL * AT_STR];   //  4608 B
    __shared__ float asum_l[4][32];               //   512 B
    const int t    = threadIdx.x;
    const int lane = t & 63;
    const int wv   = t >> 6;
    const int l15  = lane & 15;
    const int quad = lane >> 4;
    const int n0   = blockIdx.x * 64;
    const int b    = n0 / HW;          // uniform per block (64 | 3136)
    const int ch   = blockIdx.x % NCHK;

    f32x4 acc0 = {0.f, 0.f, 0.f, 0.f};
    f32x4 acc1 = {0.f, 0.f, 0.f, 0.f};

    // ---- phase-1: 2-deep software pipeline over 4 d-chunks (fully unrolled)
    float4 pxA[8], pxB[8], wcA[4], wcB[4];
    LOAD_PX(pxA, 0);    LOAD_WC(wcA, 0);
    LOAD_PX(pxB, 128);  LOAD_WC(wcB, 128);

    P1_STAGE(pxA, wcA);                    // c=0
    LOAD_PX(pxA, 256);  LOAD_WC(wcA, 256); // prefetch c=2
    P1_MFMA();
    P1_STAGE(pxB, wcB);                    // c=1
    LOAD_PX(pxB, 384);  LOAD_WC(wcB, 384); // prefetch c=3
    P1_MFMA();
    P1_STAGE(pxA, wcA);                    // c=2
    P1_MFMA();
    P1_STAGE(pxB, wcB);                    // c=3
    P1_MFMA();

    // ---- softmax over 32 k per position (row = quad*4+reg, col k = l15/+16)
    // a -> aT[k][pos] bf16 in LDS (phase-2 B operand); a_sum via block atomic.
    float at0 = 0.f, at1 = 0.f;
#pragma unroll
    for (int r = 0; r < 4; ++r) {
        float m = fmaxf(acc0[r], acc1[r]);
        m = fmaxf(m, __shfl_xor(m, 1));
        m = fmaxf(m, __shfl_xor(m, 2));
        m = fmaxf(m, __shfl_xor(m, 4));
        m = fmaxf(m, __shfl_xor(m, 8));
        float e0 = __expf(acc0[r] - m);
        float e1 = __expf(acc1[r] - m);
        float s = e0 + e1;
        s += __shfl_xor(s, 1);
        s += __shfl_xor(s, 2);
        s += __shfl_xor(s, 4);
        s += __shfl_xor(s, 8);
        float inv = 1.f / s;
        float a0 = e0 * inv, a1 = e1 * inv;
        const int pos = wv * 16 + quad * 4 + r;        // local 0..63
        aT[l15 * AT_STR + pos]        = f2bf(a0);
        aT[(16 + l15) * AT_STR + pos] = f2bf(a1);
        at0 += a0; at1 += a1;
    }
    at0 += __shfl_xor(at0, 16); at0 += __shfl_xor(at0, 32);
    at1 += __shfl_xor(at1, 16); at1 += __shfl_xor(at1, 32);
    if (quad == 0) {
        asum_l[wv][l15]      = at0;
        asum_l[wv][16 + l15] = at1;
    }

    // ---- phase-2: 2-deep pipeline, v[d,k] = sum_pos x[pos,d]*a[pos,k]
    const int dl  = t & 127;           // local d row this thread stages
    const int pg0 = t >> 7;            // 0/1: which half of the 4-pos groups
    const float* xb = x + (size_t)n0 * DIM + dl;
    float* vp = vpart + (size_t)ch * SLABF + (size_t)b * DIM * KCL;

    float pfA[32], pfB[32];
    LOAD_PF(pfA, 0);
    LOAD_PF(pfB, 128);

    __syncthreads();                   // asum_l + aT visible block-wide
    if (t < 32)
        atomAddF(&a_sum[b * KCL + t],
                 asum_l[0][t] + asum_l[1][t] + asum_l[2][t] + asum_l[3][t]);

    P2_STAGE(pfA);                     // dc=0
    LOAD_PF(pfA, 256);                 // prefetch dc=256
    P2_MFMA_STORE(0);
    P2_STAGE(pfB);                     // dc=128
    LOAD_PF(pfB, 384);                 // prefetch dc=384
    P2_MFMA_STORE(128);
    P2_STAGE(pfA);                     // dc=256
    P2_MFMA_STORE(256);
    P2_STAGE(pfB);                     // dc=384
    P2_MFMA_STORE(384);
}

// ---------------- K3: reduce chunk slabs + C*a_sum + intra-normalize -------
// grid 1024, block 256: 8 rows x 32 k; thread = one (row,k) cell. Compile-time
// 49-slab loop, unroll x4, 4 accumulators => ~16 loads in flight (the R9
// runtime-bound loop serialized the 49 L3/HBM hits).
__global__ __launch_bounds__(256) void k_norm1(const float* __restrict__ vpart,
                                               const float* __restrict__ a_sum,
                                               const float* __restrict__ Cc,
                                               float* __restrict__ out,
                                               float* __restrict__ ssq) {
    const int t = threadIdx.x;
    const int row = blockIdx.x * 8 + (t >> 5);
    const int k = t & 31;
    const int b = row >> 9;            // uniform per block (8 | 512)
    const int d = row & 511;

    const float* vp = vpart + (size_t)row * KCL + k;
    float s0 = 0.f, s1 = 0.f, s2 = 0.f, s3 = 0.f;
#pragma unroll
    for (int ps = 0; ps < 48; ps += 4) {
        s0 += vp[(size_t)(ps + 0) * SLABF];
        s1 += vp[(size_t)(ps + 1) * SLABF];
        s2 += vp[(size_t)(ps + 2) * SLABF];
        s3 += vp[(size_t)(ps + 3) * SLABF];
    }
    s0 += vp[(size_t)48 * SLABF];
    float v = (s0 + s1) + (s2 + s3) + Cc[d * KCL + k] * a_sum[b * KCL + k];

    float ss = v * v;
    ss += __shfl_xor(ss, 1, 32);  ss += __shfl_xor(ss, 2, 32);
    ss += __shfl_xor(ss, 4, 32);  ss += __shfl_xor(ss, 8, 32);
    ss += __shfl_xor(ss, 16, 32);
    float inv = 1.f / fmaxf(sqrtf(ss), 1e-12f);
    float r = v * inv;
    out[(size_t)row * KCL + k] = r;

    float bs = r * r;
    for (int off = 32; off > 0; off >>= 1) bs += __shfl_down(bs, off, 64);
    __shared__ float red[4];
    if ((t & 63) == 0) red[t >> 6] = bs;
    __syncthreads();
    if (t == 0) atomAddF(&ssq[b], (red[0] + red[1]) + (red[2] + red[3]));
}

// ---------------- K4: final global L2 normalize ----------------
__global__ __launch_bounds__(256) void k_norm2(float* __restrict__ out,
                                               const float* __restrict__ ssq) {
    const int i4 = blockIdx.x * 256 + threadIdx.x;
    const int b = i4 >> 12;
    float inv = 1.f / fmaxf(sqrtf(ssq[b]), 1e-12f);
    float4 v = *(float4*)(out + (size_t)i4 * 4);
    v.x *= inv; v.y *= inv; v.z *= inv; v.w *= inv;
    *(float4*)(out + (size_t)i4 * 4) = v;
}

extern "C" void kernel_launch(void* const* d_in, const int* in_sizes, int n_in,
                              void* d_out, int out_size, void* d_ws, size_t ws_size,
                              hipStream_t stream) {
    const float* x  = (const float*)d_in[0];
    const float* Wc = (const float*)d_in[1];
    const float* Cc = (const float*)d_in[2];
    float* out = (float*)d_out;

    // ws: vpart 49 padded slabs (51.5 MB) | a_sum (2 KB) | ssq (64 B)
    char* ws = (char*)d_ws;
    float* vpart = (float*)ws;
    float* a_sum = (float*)(ws + (size_t)NCHK * SLABF * 4);
    float* ssq   = (float*)(ws + (size_t)NCHK * SLABF * 4 + 2048);

    hipMemsetAsync(a_sum, 0, 2048 + 64, stream);

    k_sax  <<<784, 256, 0, stream>>>(x, Wc, vpart, a_sum);
    k_norm1<<<1024, 256, 0, stream>>>(vpart, a_sum, Cc, out, ssq);
    k_norm2<<<256, 256, 0, stream>>>(out, ssq);
}